// Round 3
// baseline (195.038 us; speedup 1.0000x reference)
//
#include <hip/hip_runtime.h>
#include <math.h>

#define N_NODES 100000
#define N_EDGES 1600000
#define D 64
#define RPB 128                  // rows per bucket
#define NBUK 782                 // ceil(N_NODES/128)
#define CAP 3072                 // LDS edge buffer (bucket mean 2048, +22 sigma)
#define NGB 782                  // gemm blocks (128 rows each)
#define NHB 392                  // sort blocks (FIRST in grid: long poles start at t=0)
#define EPB 4096                 // edges per sort block (392*4096 >= 1.6M)
#define POFF_STRIDE 392          // row stride of poff[b][hb]

typedef unsigned int u32;
typedef unsigned short u16;

static __device__ __forceinline__ u32 f2bf(float x) {   // RNE fp32->bf16 (low 16)
    u32 u = __float_as_uint(x);
    u32 r = u + 0x7FFFu + ((u >> 16) & 1u);
    return r >> 16;
}
static __device__ __forceinline__ u32 pack2(float a, float b) {
    return f2bf(a) | (f2bf(b) << 16);
}
static __device__ __forceinline__ float bflo(u32 u) { return __uint_as_float(u << 16); }
static __device__ __forceinline__ float bfhi(u32 u) { return __uint_as_float(u & 0xFFFF0000u); }
static __device__ __forceinline__ float selu(float x) {
    const float scale = 1.0507009873554805f;
    const float alpha = 1.6732632423543772f;
    return x > 0.f ? scale * x : scale * alpha * (expf(x) - 1.f);
}

// ---------------------------------------------------------------------------
// K1 fused. Blocks [0,392): in-LDS counting sort of 4096 edges by 128-row
// bucket -> private contiguous sedge region + 783 bucket offsets. erow is
// read twice from global (L2-hot 16KB) instead of LDS-staged: LDS drops
// 43.2->16 KB so gemm blocks co-schedule 4/CU. Sort blocks lead the grid so
// their long duration overlaps the gemm stream instead of forming a tail.
// Blocks [392,1174): bf16 h = feat @ kern (register-tiled 4r x 8c, kern in
// LDS, feat streamed from global).
// ---------------------------------------------------------------------------
__global__ __launch_bounds__(256) void fused_gemm_sort(
    const float* __restrict__ feat, const float* __restrict__ kern,
    const int* __restrict__ erow, const int* __restrict__ ecol,
    const float* __restrict__ eval, u16* __restrict__ hbf,
    int2* __restrict__ sedge, u32* __restrict__ poff)
{
    __shared__ u32 smem[4096];   // 16 KB: gemm kernel tile OR sort tables
    const int t = threadIdx.x;

    if (blockIdx.x >= NHB) {
        float* ks = (float*)smem;   // 64x64 kernel, row-major [k][c]
        {
            const float4* k4 = (const float4*)kern;
            float4* ks4 = (float4*)ks;
            #pragma unroll
            for (int i = 0; i < 4; i++) ks4[t + 256 * i] = k4[t + 256 * i];
        }
        __syncthreads();

        const int cgi  = t & 7;                      // 8 col-groups (8 cols)
        const int rg   = t >> 3;                     // 32 row-groups (4 rows)
        const int row0 = (blockIdx.x - NHB) * RPB + rg * 4;

        float4 acc[4][2];
        #pragma unroll
        for (int r = 0; r < 4; r++)
            #pragma unroll
            for (int i = 0; i < 2; i++)
                acc[r][i] = make_float4(0.f, 0.f, 0.f, 0.f);

        #pragma unroll 4
        for (int s = 0; s < 16; s++) {               // k4-step: 4 k-values
            float4 f[4];
            #pragma unroll
            for (int r = 0; r < 4; r++) {
                int row = min(row0 + r, N_NODES - 1);
                f[r] = ((const float4*)(feat + (size_t)row * D))[s];
            }
            float4 kk[4][2];
            #pragma unroll
            for (int kv = 0; kv < 4; kv++)
                #pragma unroll
                for (int i = 0; i < 2; i++)
                    kk[kv][i] = ((const float4*)(ks + (s * 4 + kv) * D))[cgi * 2 + i];
            #pragma unroll
            for (int r = 0; r < 4; r++) {
                #pragma unroll
                for (int kv = 0; kv < 4; kv++) {
                    float fv = (&f[r].x)[kv];
                    #pragma unroll
                    for (int i = 0; i < 2; i++) {
                        acc[r][i].x += fv * kk[kv][i].x;
                        acc[r][i].y += fv * kk[kv][i].y;
                        acc[r][i].z += fv * kk[kv][i].z;
                        acc[r][i].w += fv * kk[kv][i].w;
                    }
                }
            }
        }

        #pragma unroll
        for (int r = 0; r < 4; r++) {
            int row = row0 + r;
            if (row < N_NODES) {
                uint4 o;
                o.x = pack2(acc[r][0].x, acc[r][0].y);
                o.y = pack2(acc[r][0].z, acc[r][0].w);
                o.z = pack2(acc[r][1].x, acc[r][1].y);
                o.w = pack2(acc[r][1].z, acc[r][1].w);
                ((uint4*)(hbf + (size_t)row * D))[cgi] = o;
            }
        }
    } else {
        u32* c    = smem;                 // 782 counts
        u32* o    = c + NBUK;             // 783 offsets
        u32* cu   = o + NBUK + 1;         // 782 cursors
        u32* part = cu + NBUK;            // 256 scan partials  (total 2603 u32)

        for (int i = t; i < NBUK; i += 256) c[i] = 0u;
        __syncthreads();

        const int hb   = blockIdx.x;
        const int base = hb * EPB;

        // pass 1: bucket count (native u32 LDS atomics), coalesced erow reads
        #pragma unroll
        for (int k = 0; k < 16; k++) {
            int i = base + k * 256 + t;
            if (i < N_EDGES) atomicAdd(&c[(u32)erow[i] >> 7], 1u);
        }
        __syncthreads();

        // blocked exclusive scan over 782 counts (4 per thread + 256-wide HS)
        const int i0 = t * 4;
        {
            u32 p = 0u;
            #pragma unroll
            for (int j = 0; j < 4; j++) { int i = i0 + j; if (i < NBUK) p += c[i]; }
            part[t] = p;
        }
        __syncthreads();
        for (int d = 1; d < 256; d <<= 1) {
            u32 a = (t >= d) ? part[t - d] : 0u;
            __syncthreads();
            part[t] += a;
            __syncthreads();
        }
        {
            u32 run = (t > 0) ? part[t - 1] : 0u;
            #pragma unroll
            for (int j = 0; j < 4; j++) {
                int i = i0 + j;
                if (i < NBUK) { o[i] = run; cu[i] = run; run += c[i]; }
            }
            if (t == 255) o[NBUK] = part[255];   // total edges in this block
        }
        __syncthreads();

        // pass 2: re-read erow (L2-hot) + scatter into private region
        #pragma unroll
        for (int k = 0; k < 16; k++) {
            int i = base + k * 256 + t;
            if (i < N_EDGES) {
                u32 r = (u32)erow[i];
                u32 rk = atomicAdd(&cu[r >> 7], 1u);
                sedge[(size_t)hb * EPB + rk] =
                    make_int2(ecol[i] | (int)((r & 127u) << 17),
                              __float_as_int(eval[i]));
            }
        }

        // publish 783 offsets, transposed for coalesced agg reads
        for (int i = t; i <= NBUK; i += 256)
            poff[(size_t)i * POFF_STRIDE + hb] = o[i];
    }
}

// ---------------------------------------------------------------------------
// K2: aggregation, sorted-register design, no cross-lane reduce.
//  Pass 1: count edges per local row directly from global sedge.
//  Scan:   128-wide exclusive scan of row counts.
//  Pass 2: re-read sedge (L2-hot) and scatter row-sorted into eB.
//  Phase C: one row per 8-lane group (128 rows concurrent), 8 dims/lane,
//          serial walk unrolled x4 (avg degree 16 -> ~4 chain steps).
// ---------------------------------------------------------------------------
__global__ __launch_bounds__(1024) void agg_kernel(
    const u32* __restrict__ poff, const int2* __restrict__ sedge,
    const u16* __restrict__ hbf, const float* __restrict__ skip,
    const float* __restrict__ bias, float* __restrict__ out)
{
    __shared__ int2 eB[CAP];          // 24 KB row-sorted edges
    __shared__ u32 c[RPB];
    __shared__ u32 o[RPB];
    __shared__ u32 cur[RPB];
    __shared__ u32 rs0[NHB];
    __shared__ u32 rlen[NHB];

    const int t = threadIdx.x;
    const int w = t >> 6;
    const int lane = t & 63;
    const int b = blockIdx.x;

    if (t < RPB) c[t] = 0u;
    // run descriptors: coalesced 392-wide loads
    if (t < NHB) {
        u32 s0 = poff[(size_t)b * POFF_STRIDE + t];
        u32 s1 = poff[(size_t)(b + 1) * POFF_STRIDE + t];
        rs0[t]  = s0;
        rlen[t] = s1 - s0;
    }
    __syncthreads();

    // pass 1: count by local row (wave per run, coalesced global reads)
    for (int hb = w; hb < NHB; hb += 16) {
        u32 s0 = rs0[hb], len = rlen[hb];
        for (u32 j = (u32)lane; j < len; j += 64u) {
            int x = sedge[(size_t)hb * EPB + s0 + j].x;
            atomicAdd(&c[(u32)x >> 17], 1u);
        }
    }
    __syncthreads();

    // exclusive scan over 128 row counts
    if (t < RPB) o[t] = c[t];
    __syncthreads();
    for (int d = 1; d < RPB; d <<= 1) {
        u32 a = 0u;
        if (t < RPB && t >= d) a = o[t - d];
        __syncthreads();
        if (t < RPB) o[t] += a;
        __syncthreads();
    }
    if (t < RPB) { u32 e = o[t] - c[t]; o[t] = e; cur[t] = e; }
    __syncthreads();

    // pass 2: re-read (L2-hot) and scatter row-sorted into eB
    for (int hb = w; hb < NHB; hb += 16) {
        u32 s0 = rs0[hb], len = rlen[hb];
        for (u32 j = (u32)lane; j < len; j += 64u) {
            int2 e = sedge[(size_t)hb * EPB + s0 + j];
            u32 rl = (u32)e.x >> 17;
            u32 rk = atomicAdd(&cur[rl], 1u);
            if (rk < CAP) eB[rk] = make_int2(e.x & 0x1FFFF, e.y);
        }
    }
    __syncthreads();

    // phase C: one row per 8-lane group, 8 dims/lane, no cross-lane reduce
    const int rows = min(RPB, N_NODES - b * RPB);
    const int g  = t >> 3;            // 0..127: local row
    const int dg = t & 7;             // dim group (8 dims = one uint4)

    float a0 = 0.f, a1 = 0.f, a2 = 0.f, a3 = 0.f;
    float a4 = 0.f, a5 = 0.f, a6 = 0.f, a7 = 0.f;

    u32 jb = 0u, jend = 0u;
    if (g < rows) {
        jb = o[g];
        jend = min(jb + c[g], (u32)CAP);
    }

    u32 j = jb;
    for (; j + 3u < jend; j += 4u) {
        int2 e0 = eB[j];                  // 8-lane broadcast (conflict-free)
        int2 e1 = eB[j + 1u];
        int2 e2 = eB[j + 2u];
        int2 e3 = eB[j + 3u];
        float v0 = __int_as_float(e0.y);
        float v1 = __int_as_float(e1.y);
        float v2 = __int_as_float(e2.y);
        float v3 = __int_as_float(e3.y);
        uint4 h0 = ((const uint4*)(hbf + (size_t)e0.x * D))[dg];
        uint4 h1 = ((const uint4*)(hbf + (size_t)e1.x * D))[dg];
        uint4 h2 = ((const uint4*)(hbf + (size_t)e2.x * D))[dg];
        uint4 h3 = ((const uint4*)(hbf + (size_t)e3.x * D))[dg];
        a0 += v0 * bflo(h0.x); a1 += v0 * bfhi(h0.x);
        a2 += v0 * bflo(h0.y); a3 += v0 * bfhi(h0.y);
        a4 += v0 * bflo(h0.z); a5 += v0 * bfhi(h0.z);
        a6 += v0 * bflo(h0.w); a7 += v0 * bfhi(h0.w);
        a0 += v1 * bflo(h1.x); a1 += v1 * bfhi(h1.x);
        a2 += v1 * bflo(h1.y); a3 += v1 * bfhi(h1.y);
        a4 += v1 * bflo(h1.z); a5 += v1 * bfhi(h1.z);
        a6 += v1 * bflo(h1.w); a7 += v1 * bfhi(h1.w);
        a0 += v2 * bflo(h2.x); a1 += v2 * bfhi(h2.x);
        a2 += v2 * bflo(h2.y); a3 += v2 * bfhi(h2.y);
        a4 += v2 * bflo(h2.z); a5 += v2 * bfhi(h2.z);
        a6 += v2 * bflo(h2.w); a7 += v2 * bfhi(h2.w);
        a0 += v3 * bflo(h3.x); a1 += v3 * bfhi(h3.x);
        a2 += v3 * bflo(h3.y); a3 += v3 * bfhi(h3.y);
        a4 += v3 * bflo(h3.z); a5 += v3 * bfhi(h3.z);
        a6 += v3 * bflo(h3.w); a7 += v3 * bfhi(h3.w);
    }
    for (; j < jend; j++) {
        int2 e0 = eB[j];
        float v0 = __int_as_float(e0.y);
        uint4 h0 = ((const uint4*)(hbf + (size_t)e0.x * D))[dg];
        a0 += v0 * bflo(h0.x); a1 += v0 * bfhi(h0.x);
        a2 += v0 * bflo(h0.y); a3 += v0 * bfhi(h0.y);
        a4 += v0 * bflo(h0.z); a5 += v0 * bfhi(h0.z);
        a6 += v0 * bflo(h0.w); a7 += v0 * bfhi(h0.w);
    }

    // epilogue: all lanes active (8 lanes x 8 dims per row)
    if (g < rows) {
        const int grow = b * RPB + g;
        uint4 hr = ((const uint4*)(hbf + (size_t)grow * D))[dg];
        float4 s0 = ((const float4*)skip)[2 * dg];
        float4 s1 = ((const float4*)skip)[2 * dg + 1];
        float4 b0 = ((const float4*)bias)[2 * dg];
        float4 b1 = ((const float4*)bias)[2 * dg + 1];
        float4 x0, x1;
        x0.x = selu(bflo(hr.x) * s0.x + b0.x + a0);
        x0.y = selu(bfhi(hr.x) * s0.y + b0.y + a1);
        x0.z = selu(bflo(hr.y) * s0.z + b0.z + a2);
        x0.w = selu(bfhi(hr.y) * s0.w + b0.w + a3);
        x1.x = selu(bflo(hr.z) * s1.x + b1.x + a4);
        x1.y = selu(bfhi(hr.z) * s1.y + b1.y + a5);
        x1.z = selu(bflo(hr.w) * s1.z + b1.z + a6);
        x1.w = selu(bfhi(hr.w) * s1.w + b1.w + a7);
        ((float4*)(out + (size_t)grow * D))[2 * dg]     = x0;
        ((float4*)(out + (size_t)grow * D))[2 * dg + 1] = x1;
    }
}

extern "C" void kernel_launch(void* const* d_in, const int* in_sizes, int n_in,
                              void* d_out, int out_size, void* d_ws, size_t ws_size,
                              hipStream_t stream)
{
    const float* feat = (const float*)d_in[0];
    const float* kern = (const float*)d_in[1];
    const float* bias = (const float*)d_in[2];
    const float* skip = (const float*)d_in[3];
    const int*   erow = (const int*)d_in[4];
    const int*   ecol = (const int*)d_in[5];
    const float* eval = (const float*)d_in[6];
    float* out = (float*)d_out;

    // workspace layout (all segments 16B-aligned)
    u16*  hbf   = (u16*)d_ws;                            // 6,400,000 u16 (12.8 MB)
    u32*  poff  = (u32*)(hbf + (size_t)N_NODES * D);     // 783*392 = 306,936 u32 (1.23 MB)
    int2* sedge = (int2*)(poff + 306936);                // 392*4096 int2 (12.85 MB)
    // total ~26.9 MB

    hipLaunchKernelGGL(fused_gemm_sort, dim3(NGB + NHB), dim3(256), 0, stream,
                       feat, kern, erow, ecol, eval, hbf, sedge, poff);
    hipLaunchKernelGGL(agg_kernel, dim3(NBUK), dim3(1024), 0, stream,
                       poff, sedge, hbf, skip, bias, out);
}

// Round 4
// 173.655 us; speedup vs baseline: 1.1231x; 1.1231x over previous
//
#include <hip/hip_runtime.h>
#include <math.h>

#define N_NODES 100000
#define N_EDGES 1600000
#define D 64
#define RPB 128                  // rows per bucket
#define NBUK 782                 // ceil(N_NODES/128)
#define CAP 3072                 // LDS edge buffer (bucket mean 2048, +22 sigma)
#define NGB 782                  // gemm blocks (128 rows each)
#define NHB 392                  // sort blocks (FIRST in grid: long poles start at t=0)
#define EPB 4096                 // edges per sort block (392*4096 >= 1.6M)
#define POFF_STRIDE 392          // row stride of poff[b][hb]

typedef unsigned int u32;
typedef unsigned short u16;

static __device__ __forceinline__ u32 f2bf(float x) {   // RNE fp32->bf16 (low 16)
    u32 u = __float_as_uint(x);
    u32 r = u + 0x7FFFu + ((u >> 16) & 1u);
    return r >> 16;
}
static __device__ __forceinline__ u32 pack2(float a, float b) {
    return f2bf(a) | (f2bf(b) << 16);
}
static __device__ __forceinline__ float bflo(u32 u) { return __uint_as_float(u << 16); }
static __device__ __forceinline__ float bfhi(u32 u) { return __uint_as_float(u & 0xFFFF0000u); }
static __device__ __forceinline__ float selu(float x) {
    const float scale = 1.0507009873554805f;
    const float alpha = 1.6732632423543772f;
    return x > 0.f ? scale * x : scale * alpha * (expf(x) - 1.f);
}

// ---------------------------------------------------------------------------
// K1 fused (unchanged from round 3). Blocks [0,392): in-LDS counting sort of
// 4096 edges by 128-row bucket -> private contiguous sedge region + bucket
// offsets. Sort blocks lead the grid so their long duration overlaps the gemm
// stream. Blocks [392,1174): bf16 h = feat @ kern (register-tiled 4r x 8c).
// ---------------------------------------------------------------------------
__global__ __launch_bounds__(256) void fused_gemm_sort(
    const float* __restrict__ feat, const float* __restrict__ kern,
    const int* __restrict__ erow, const int* __restrict__ ecol,
    const float* __restrict__ eval, u16* __restrict__ hbf,
    int2* __restrict__ sedge, u32* __restrict__ poff)
{
    __shared__ u32 smem[4096];   // 16 KB: gemm kernel tile OR sort tables
    const int t = threadIdx.x;

    if (blockIdx.x >= NHB) {
        float* ks = (float*)smem;   // 64x64 kernel, row-major [k][c]
        {
            const float4* k4 = (const float4*)kern;
            float4* ks4 = (float4*)ks;
            #pragma unroll
            for (int i = 0; i < 4; i++) ks4[t + 256 * i] = k4[t + 256 * i];
        }
        __syncthreads();

        const int cgi  = t & 7;                      // 8 col-groups (8 cols)
        const int rg   = t >> 3;                     // 32 row-groups (4 rows)
        const int row0 = (blockIdx.x - NHB) * RPB + rg * 4;

        float4 acc[4][2];
        #pragma unroll
        for (int r = 0; r < 4; r++)
            #pragma unroll
            for (int i = 0; i < 2; i++)
                acc[r][i] = make_float4(0.f, 0.f, 0.f, 0.f);

        #pragma unroll 4
        for (int s = 0; s < 16; s++) {               // k4-step: 4 k-values
            float4 f[4];
            #pragma unroll
            for (int r = 0; r < 4; r++) {
                int row = min(row0 + r, N_NODES - 1);
                f[r] = ((const float4*)(feat + (size_t)row * D))[s];
            }
            float4 kk[4][2];
            #pragma unroll
            for (int kv = 0; kv < 4; kv++)
                #pragma unroll
                for (int i = 0; i < 2; i++)
                    kk[kv][i] = ((const float4*)(ks + (s * 4 + kv) * D))[cgi * 2 + i];
            #pragma unroll
            for (int r = 0; r < 4; r++) {
                #pragma unroll
                for (int kv = 0; kv < 4; kv++) {
                    float fv = (&f[r].x)[kv];
                    #pragma unroll
                    for (int i = 0; i < 2; i++) {
                        acc[r][i].x += fv * kk[kv][i].x;
                        acc[r][i].y += fv * kk[kv][i].y;
                        acc[r][i].z += fv * kk[kv][i].z;
                        acc[r][i].w += fv * kk[kv][i].w;
                    }
                }
            }
        }

        #pragma unroll
        for (int r = 0; r < 4; r++) {
            int row = row0 + r;
            if (row < N_NODES) {
                uint4 o;
                o.x = pack2(acc[r][0].x, acc[r][0].y);
                o.y = pack2(acc[r][0].z, acc[r][0].w);
                o.z = pack2(acc[r][1].x, acc[r][1].y);
                o.w = pack2(acc[r][1].z, acc[r][1].w);
                ((uint4*)(hbf + (size_t)row * D))[cgi] = o;
            }
        }
    } else {
        u32* c    = smem;                 // 782 counts
        u32* o    = c + NBUK;             // 783 offsets
        u32* cu   = o + NBUK + 1;         // 782 cursors
        u32* part = cu + NBUK;            // 256 scan partials  (total 2603 u32)

        for (int i = t; i < NBUK; i += 256) c[i] = 0u;
        __syncthreads();

        const int hb   = blockIdx.x;
        const int base = hb * EPB;

        // pass 1: bucket count (native u32 LDS atomics), coalesced erow reads
        #pragma unroll
        for (int k = 0; k < 16; k++) {
            int i = base + k * 256 + t;
            if (i < N_EDGES) atomicAdd(&c[(u32)erow[i] >> 7], 1u);
        }
        __syncthreads();

        // blocked exclusive scan over 782 counts (4 per thread + 256-wide HS)
        const int i0 = t * 4;
        {
            u32 p = 0u;
            #pragma unroll
            for (int j = 0; j < 4; j++) { int i = i0 + j; if (i < NBUK) p += c[i]; }
            part[t] = p;
        }
        __syncthreads();
        for (int d = 1; d < 256; d <<= 1) {
            u32 a = (t >= d) ? part[t - d] : 0u;
            __syncthreads();
            part[t] += a;
            __syncthreads();
        }
        {
            u32 run = (t > 0) ? part[t - 1] : 0u;
            #pragma unroll
            for (int j = 0; j < 4; j++) {
                int i = i0 + j;
                if (i < NBUK) { o[i] = run; cu[i] = run; run += c[i]; }
            }
            if (t == 255) o[NBUK] = part[255];   // total edges in this block
        }
        __syncthreads();

        // pass 2: re-read erow (L2-hot) + scatter into private region
        #pragma unroll
        for (int k = 0; k < 16; k++) {
            int i = base + k * 256 + t;
            if (i < N_EDGES) {
                u32 r = (u32)erow[i];
                u32 rk = atomicAdd(&cu[r >> 7], 1u);
                sedge[(size_t)hb * EPB + rk] =
                    make_int2(ecol[i] | (int)((r & 127u) << 17),
                              __float_as_int(eval[i]));
            }
        }

        // publish 783 offsets, transposed for coalesced agg reads
        for (int i = t; i <= NBUK; i += 256)
            poff[(size_t)i * POFF_STRIDE + hb] = o[i];
    }
}

// ---------------------------------------------------------------------------
// K2 v5: aggregation, edge-parallel staging (run length independent).
//  1) 392-wide coalesced run-descriptor load; 512-wide scan -> rb[] (edge
//     index -> run map), cnt.
//  2) Stage: edge-parallel over cnt; each thread binary-searches its run in
//     LDS (9 steps, read-only), loads the edge ONCE from global (coalesced
//     chunks), writes eA, counts its row.  [replaces serial wave-per-run
//     passes that idled ~59/64 lanes per run]
//  3) 128-wide row scan; LDS->LDS edge-parallel scatter into row-sorted eB.
//  4) Phase C: one row per 8-lane group, 8 dims/lane, x4 unroll, no
//     cross-lane reduce; epilogue uses all 1024 lanes.
// ---------------------------------------------------------------------------
__global__ __launch_bounds__(1024) void agg_kernel(
    const u32* __restrict__ poff, const int2* __restrict__ sedge,
    const u16* __restrict__ hbf, const float* __restrict__ skip,
    const float* __restrict__ bias, float* __restrict__ out)
{
    __shared__ int2 eA[CAP];          // 24 KB staged (bucket-contiguous)
    __shared__ int2 eB[CAP];          // 24 KB row-sorted
    __shared__ u32 c[RPB];
    __shared__ u32 o[RPB];
    __shared__ u32 cur[RPB];
    __shared__ u32 rs0[NHB];          // run start within its sedge region
    __shared__ u32 rb[NHB + 1];       // exclusive scan of run lengths
    __shared__ u32 scn[512];

    const int t = threadIdx.x;
    const int b = blockIdx.x;

    if (t < RPB) c[t] = 0u;
    // run descriptors: coalesced 392-wide loads
    u32 mylen = 0u;
    if (t < NHB) {
        u32 s0 = poff[(size_t)b * POFF_STRIDE + t];
        u32 s1 = poff[(size_t)(b + 1) * POFF_STRIDE + t];
        rs0[t] = s0;
        mylen  = s1 - s0;
    }
    if (t < 512) scn[t] = (t < NHB) ? mylen : 0u;
    __syncthreads();

    // 512-wide Hillis-Steele inclusive scan of run lengths
    for (int d = 1; d < 512; d <<= 1) {
        u32 a = 0u;
        if (t < 512 && t >= d) a = scn[t - d];
        __syncthreads();
        if (t < 512) scn[t] += a;
        __syncthreads();
    }
    if (t == 0) rb[0] = 0u;
    if (t < NHB) rb[t + 1] = scn[t];
    __syncthreads();

    const u32 cnt = min(rb[NHB], (u32)CAP);

    // stage: edge-parallel, binary search run, single global read, row count
    for (u32 j = (u32)t; j < cnt; j += 1024u) {
        u32 lo = 0u, hi = (u32)NHB;            // invariant rb[lo] <= j < rb[hi]
        while (hi - lo > 1u) {
            u32 mid = (lo + hi) >> 1;
            if (rb[mid] <= j) lo = mid; else hi = mid;
        }
        int2 e = sedge[(size_t)lo * EPB + rs0[lo] + (j - rb[lo])];
        eA[j] = e;
        atomicAdd(&c[(u32)e.x >> 17], 1u);
    }
    __syncthreads();

    // exclusive scan over 128 row counts
    if (t < RPB) o[t] = c[t];
    __syncthreads();
    for (int d = 1; d < RPB; d <<= 1) {
        u32 a = 0u;
        if (t < RPB && t >= d) a = o[t - d];
        __syncthreads();
        if (t < RPB) o[t] += a;
        __syncthreads();
    }
    if (t < RPB) { u32 e = o[t] - c[t]; o[t] = e; cur[t] = e; }
    __syncthreads();

    // scatter LDS->LDS into row-sorted eB (rk < cnt <= CAP by construction)
    for (u32 j = (u32)t; j < cnt; j += 1024u) {
        int2 e = eA[j];
        u32 rl = (u32)e.x >> 17;
        u32 rk = atomicAdd(&cur[rl], 1u);
        eB[rk] = make_int2(e.x & 0x1FFFF, e.y);
    }
    __syncthreads();

    // phase C: one row per 8-lane group, 8 dims/lane, no cross-lane reduce
    const int rows = min(RPB, N_NODES - b * RPB);
    const int g  = t >> 3;            // 0..127: local row
    const int dg = t & 7;             // dim group (8 dims = one uint4)

    float a0 = 0.f, a1 = 0.f, a2 = 0.f, a3 = 0.f;
    float a4 = 0.f, a5 = 0.f, a6 = 0.f, a7 = 0.f;

    u32 jb = 0u, jend = 0u;
    if (g < rows) {
        jb = o[g];
        jend = min(jb + c[g], (u32)CAP);
    }

    u32 j = jb;
    for (; j + 3u < jend; j += 4u) {
        int2 e0 = eB[j];                  // 8-lane broadcast (conflict-free)
        int2 e1 = eB[j + 1u];
        int2 e2 = eB[j + 2u];
        int2 e3 = eB[j + 3u];
        float v0 = __int_as_float(e0.y);
        float v1 = __int_as_float(e1.y);
        float v2 = __int_as_float(e2.y);
        float v3 = __int_as_float(e3.y);
        uint4 h0 = ((const uint4*)(hbf + (size_t)e0.x * D))[dg];
        uint4 h1 = ((const uint4*)(hbf + (size_t)e1.x * D))[dg];
        uint4 h2 = ((const uint4*)(hbf + (size_t)e2.x * D))[dg];
        uint4 h3 = ((const uint4*)(hbf + (size_t)e3.x * D))[dg];
        a0 += v0 * bflo(h0.x); a1 += v0 * bfhi(h0.x);
        a2 += v0 * bflo(h0.y); a3 += v0 * bfhi(h0.y);
        a4 += v0 * bflo(h0.z); a5 += v0 * bfhi(h0.z);
        a6 += v0 * bflo(h0.w); a7 += v0 * bfhi(h0.w);
        a0 += v1 * bflo(h1.x); a1 += v1 * bfhi(h1.x);
        a2 += v1 * bflo(h1.y); a3 += v1 * bfhi(h1.y);
        a4 += v1 * bflo(h1.z); a5 += v1 * bfhi(h1.z);
        a6 += v1 * bflo(h1.w); a7 += v1 * bfhi(h1.w);
        a0 += v2 * bflo(h2.x); a1 += v2 * bfhi(h2.x);
        a2 += v2 * bflo(h2.y); a3 += v2 * bfhi(h2.y);
        a4 += v2 * bflo(h2.z); a5 += v2 * bfhi(h2.z);
        a6 += v2 * bflo(h2.w); a7 += v2 * bfhi(h2.w);
        a0 += v3 * bflo(h3.x); a1 += v3 * bfhi(h3.x);
        a2 += v3 * bflo(h3.y); a3 += v3 * bfhi(h3.y);
        a4 += v3 * bflo(h3.z); a5 += v3 * bfhi(h3.z);
        a6 += v3 * bflo(h3.w); a7 += v3 * bfhi(h3.w);
    }
    for (; j < jend; j++) {
        int2 e0 = eB[j];
        float v0 = __int_as_float(e0.y);
        uint4 h0 = ((const uint4*)(hbf + (size_t)e0.x * D))[dg];
        a0 += v0 * bflo(h0.x); a1 += v0 * bfhi(h0.x);
        a2 += v0 * bflo(h0.y); a3 += v0 * bfhi(h0.y);
        a4 += v0 * bflo(h0.z); a5 += v0 * bfhi(h0.z);
        a6 += v0 * bflo(h0.w); a7 += v0 * bfhi(h0.w);
    }

    // epilogue: all lanes active (8 lanes x 8 dims per row)
    if (g < rows) {
        const int grow = b * RPB + g;
        uint4 hr = ((const uint4*)(hbf + (size_t)grow * D))[dg];
        float4 s0 = ((const float4*)skip)[2 * dg];
        float4 s1 = ((const float4*)skip)[2 * dg + 1];
        float4 b0 = ((const float4*)bias)[2 * dg];
        float4 b1 = ((const float4*)bias)[2 * dg + 1];
        float4 x0, x1;
        x0.x = selu(bflo(hr.x) * s0.x + b0.x + a0);
        x0.y = selu(bfhi(hr.x) * s0.y + b0.y + a1);
        x0.z = selu(bflo(hr.y) * s0.z + b0.z + a2);
        x0.w = selu(bfhi(hr.y) * s0.w + b0.w + a3);
        x1.x = selu(bflo(hr.z) * s1.x + b1.x + a4);
        x1.y = selu(bfhi(hr.z) * s1.y + b1.y + a5);
        x1.z = selu(bflo(hr.w) * s1.z + b1.z + a6);
        x1.w = selu(bfhi(hr.w) * s1.w + b1.w + a7);
        ((float4*)(out + (size_t)grow * D))[2 * dg]     = x0;
        ((float4*)(out + (size_t)grow * D))[2 * dg + 1] = x1;
    }
}

extern "C" void kernel_launch(void* const* d_in, const int* in_sizes, int n_in,
                              void* d_out, int out_size, void* d_ws, size_t ws_size,
                              hipStream_t stream)
{
    const float* feat = (const float*)d_in[0];
    const float* kern = (const float*)d_in[1];
    const float* bias = (const float*)d_in[2];
    const float* skip = (const float*)d_in[3];
    const int*   erow = (const int*)d_in[4];
    const int*   ecol = (const int*)d_in[5];
    const float* eval = (const float*)d_in[6];
    float* out = (float*)d_out;

    // workspace layout (all segments 16B-aligned)
    u16*  hbf   = (u16*)d_ws;                            // 6,400,000 u16 (12.8 MB)
    u32*  poff  = (u32*)(hbf + (size_t)N_NODES * D);     // 783*392 = 306,936 u32 (1.23 MB)
    int2* sedge = (int2*)(poff + 306936);                // 392*4096 int2 (12.85 MB)
    // total ~26.9 MB

    hipLaunchKernelGGL(fused_gemm_sort, dim3(NGB + NHB), dim3(256), 0, stream,
                       feat, kern, erow, ecol, eval, hbf, sedge, poff);
    hipLaunchKernelGGL(agg_kernel, dim3(NBUK), dim3(1024), 0, stream,
                       poff, sedge, hbf, skip, bias, out);
}

// Round 5
// 168.310 us; speedup vs baseline: 1.1588x; 1.0318x over previous
//
#include <hip/hip_runtime.h>
#include <math.h>

#define N_NODES 100000
#define N_EDGES 1600000
#define D 64
#define RPB 128                  // rows per bucket
#define NBUK 782                 // ceil(N_NODES/128)
#define CAP 3072                 // LDS edge buffer (bucket mean 2048, +22 sigma)
#define NGB 782                  // gemm blocks (128 rows each)
#define NHB 784                  // sort blocks (FIRST in grid: poles start at t=0)
#define EPB 2048                 // edges per sort block (784*2048 >= 1.6M)
#define POFF_ROW 784             // u32 stride of poff[hb][*] (hb-major, padded)

typedef unsigned int u32;
typedef unsigned short u16;

static __device__ __forceinline__ u32 f2bf(float x) {   // RNE fp32->bf16 (low 16)
    u32 u = __float_as_uint(x);
    u32 r = u + 0x7FFFu + ((u >> 16) & 1u);
    return r >> 16;
}
static __device__ __forceinline__ u32 pack2(float a, float b) {
    return f2bf(a) | (f2bf(b) << 16);
}
static __device__ __forceinline__ float bflo(u32 u) { return __uint_as_float(u << 16); }
static __device__ __forceinline__ float bfhi(u32 u) { return __uint_as_float(u & 0xFFFF0000u); }
static __device__ __forceinline__ float selu(float x) {
    const float scale = 1.0507009873554805f;
    const float alpha = 1.6732632423543772f;
    return x > 0.f ? scale * x : scale * alpha * (expf(x) - 1.f);
}

// ---------------------------------------------------------------------------
// K1 fused. Blocks [0,784): in-LDS counting sort of 2048 edges (EPB halved:
// sort blocks were the kernel's long pole; K2's staging is now run-length
// independent so EPB is a free knob). erow staged in LDS during the count
// pass so the scatter pass's dependent chain starts from LDS (~120cy) not
// global (~300-900cy). poff is hb-major so the publish is a coalesced 783-u32
// streak (was 16x write-amplified strided scatter). LDS 18.6 KB -> 8
// blocks/CU, all 1566 blocks co-resident. Blocks [784,1566): bf16
// h = feat @ kern (register-tiled 4r x 8c, kern in LDS).
// ---------------------------------------------------------------------------
__global__ __launch_bounds__(256) void fused_gemm_sort(
    const float* __restrict__ feat, const float* __restrict__ kern,
    const int* __restrict__ erow, const int* __restrict__ ecol,
    const float* __restrict__ eval, u16* __restrict__ hbf,
    int2* __restrict__ sedge, u32* __restrict__ poff)
{
    __shared__ u32 smem[4656];   // 18.6 KB: gemm uses 16 KB; sort uses all
    const int t = threadIdx.x;

    if (blockIdx.x >= NHB) {
        float* ks = (float*)smem;   // 64x64 kernel, row-major [k][c]
        {
            const float4* k4 = (const float4*)kern;
            float4* ks4 = (float4*)ks;
            #pragma unroll
            for (int i = 0; i < 4; i++) ks4[t + 256 * i] = k4[t + 256 * i];
        }
        __syncthreads();

        const int cgi  = t & 7;                      // 8 col-groups (8 cols)
        const int rg   = t >> 3;                     // 32 row-groups (4 rows)
        const int row0 = (blockIdx.x - NHB) * RPB + rg * 4;

        float4 acc[4][2];
        #pragma unroll
        for (int r = 0; r < 4; r++)
            #pragma unroll
            for (int i = 0; i < 2; i++)
                acc[r][i] = make_float4(0.f, 0.f, 0.f, 0.f);

        #pragma unroll 4
        for (int s = 0; s < 16; s++) {               // k4-step: 4 k-values
            float4 f[4];
            #pragma unroll
            for (int r = 0; r < 4; r++) {
                int row = min(row0 + r, N_NODES - 1);
                f[r] = ((const float4*)(feat + (size_t)row * D))[s];
            }
            float4 kk[4][2];
            #pragma unroll
            for (int kv = 0; kv < 4; kv++)
                #pragma unroll
                for (int i = 0; i < 2; i++)
                    kk[kv][i] = ((const float4*)(ks + (s * 4 + kv) * D))[cgi * 2 + i];
            #pragma unroll
            for (int r = 0; r < 4; r++) {
                #pragma unroll
                for (int kv = 0; kv < 4; kv++) {
                    float fv = (&f[r].x)[kv];
                    #pragma unroll
                    for (int i = 0; i < 2; i++) {
                        acc[r][i].x += fv * kk[kv][i].x;
                        acc[r][i].y += fv * kk[kv][i].y;
                        acc[r][i].z += fv * kk[kv][i].z;
                        acc[r][i].w += fv * kk[kv][i].w;
                    }
                }
            }
        }

        #pragma unroll
        for (int r = 0; r < 4; r++) {
            int row = row0 + r;
            if (row < N_NODES) {
                uint4 o;
                o.x = pack2(acc[r][0].x, acc[r][0].y);
                o.y = pack2(acc[r][0].z, acc[r][0].w);
                o.z = pack2(acc[r][1].x, acc[r][1].y);
                o.w = pack2(acc[r][1].z, acc[r][1].w);
                ((uint4*)(hbf + (size_t)row * D))[cgi] = o;
            }
        }
    } else {
        u32* er   = smem;                 // 2048 staged erow (0xFFFFFFFF = OOB)
        u32* c    = er + EPB;             // 782 counts
        u32* o    = c + NBUK;             // 783 offsets
        u32* cu   = o + NBUK + 1;         // 782 cursors
        u32* part = cu + NBUK;            // 256 scan partials  (total 4651 u32)

        for (int i = t; i < NBUK; i += 256) c[i] = 0u;
        __syncthreads();

        const int hb   = blockIdx.x;
        const int base = hb * EPB;

        // pass 1: stage erow in LDS + bucket count (native u32 LDS atomics)
        #pragma unroll
        for (int k = 0; k < 8; k++) {
            int i = base + k * 256 + t;
            u32 r = 0xFFFFFFFFu;
            if (i < N_EDGES) { r = (u32)erow[i]; atomicAdd(&c[r >> 7], 1u); }
            er[k * 256 + t] = r;
        }
        __syncthreads();

        // blocked exclusive scan over 782 counts (4 per thread + 256-wide HS)
        const int i0 = t * 4;
        {
            u32 p = 0u;
            #pragma unroll
            for (int j = 0; j < 4; j++) { int i = i0 + j; if (i < NBUK) p += c[i]; }
            part[t] = p;
        }
        __syncthreads();
        for (int d = 1; d < 256; d <<= 1) {
            u32 a = (t >= d) ? part[t - d] : 0u;
            __syncthreads();
            part[t] += a;
            __syncthreads();
        }
        {
            u32 run = (t > 0) ? part[t - 1] : 0u;
            #pragma unroll
            for (int j = 0; j < 4; j++) {
                int i = i0 + j;
                if (i < NBUK) { o[i] = run; cu[i] = run; run += c[i]; }
            }
            if (t == 255) o[NBUK] = part[255];   // total edges in this block
        }
        __syncthreads();

        // pass 2: erow from LDS, scatter into private contiguous region
        #pragma unroll
        for (int k = 0; k < 8; k++) {
            int i = base + k * 256 + t;
            u32 r = er[k * 256 + t];
            if (r != 0xFFFFFFFFu) {
                u32 rk = atomicAdd(&cu[r >> 7], 1u);
                sedge[(size_t)hb * EPB + rk] =
                    make_int2(ecol[i] | (int)((r & 127u) << 17),
                              __float_as_int(eval[i]));
            }
        }

        // publish 783 offsets, hb-major: fully coalesced contiguous writes
        for (int i = t; i <= NBUK; i += 256)
            poff[(size_t)hb * POFF_ROW + i] = o[i];
    }
}

// ---------------------------------------------------------------------------
// K2: aggregation, edge-parallel staging (run-length independent).
//  1) per-thread run-descriptor gather from hb-major poff (2 loads, L2-hot);
//     1024-wide scan -> rb[] edge-index->run map.
//  2) Stage: edge-parallel; binary search run in LDS (10 steps, read-only),
//     single coalesced-chunk global edge load, write eA, count row.
//  3) 128-wide row scan; LDS->LDS edge-parallel scatter into row-sorted eB.
//  4) Phase C: one row per 8-lane group, 8 dims/lane, x4 unroll, no
//     cross-lane reduce; epilogue uses all 1024 lanes.
// ---------------------------------------------------------------------------
__global__ __launch_bounds__(1024) void agg_kernel(
    const u32* __restrict__ poff, const int2* __restrict__ sedge,
    const u16* __restrict__ hbf, const float* __restrict__ skip,
    const float* __restrict__ bias, float* __restrict__ out)
{
    __shared__ int2 eA[CAP];          // 24 KB staged (bucket-contiguous)
    __shared__ int2 eB[CAP];          // 24 KB row-sorted
    __shared__ u32 c[RPB];
    __shared__ u32 o[RPB];
    __shared__ u32 cur[RPB];
    __shared__ u32 rs0[NHB];          // run start within its sedge region
    __shared__ u32 rb[NHB + 1];       // exclusive scan of run lengths
    __shared__ u32 scn[1024];

    const int t = threadIdx.x;
    const int b = blockIdx.x;

    if (t < RPB) c[t] = 0u;
    // run descriptors: hb-major poff -> scattered 4B loads, L2-hot (97x reuse)
    u32 mylen = 0u;
    if (t < NHB) {
        const u32* pr = poff + (size_t)t * POFF_ROW + b;
        u32 s0 = pr[0];
        u32 s1 = pr[1];
        rs0[t] = s0;
        mylen  = s1 - s0;
    }
    scn[t] = (t < NHB) ? mylen : 0u;
    __syncthreads();

    // 1024-wide Hillis-Steele inclusive scan of run lengths
    for (int d = 1; d < 1024; d <<= 1) {
        u32 a = 0u;
        if (t >= d) a = scn[t - d];
        __syncthreads();
        scn[t] += a;
        __syncthreads();
    }
    if (t == 0) rb[0] = 0u;
    if (t < NHB) rb[t + 1] = scn[t];
    __syncthreads();

    const u32 cnt = min(rb[NHB], (u32)CAP);

    // stage: edge-parallel, binary search run, single global read, row count
    for (u32 j = (u32)t; j < cnt; j += 1024u) {
        u32 lo = 0u, hi = (u32)NHB;            // invariant rb[lo] <= j < rb[hi]
        while (hi - lo > 1u) {
            u32 mid = (lo + hi) >> 1;
            if (rb[mid] <= j) lo = mid; else hi = mid;
        }
        int2 e = sedge[(size_t)lo * EPB + rs0[lo] + (j - rb[lo])];
        eA[j] = e;
        atomicAdd(&c[(u32)e.x >> 17], 1u);
    }
    __syncthreads();

    // exclusive scan over 128 row counts
    if (t < RPB) o[t] = c[t];
    __syncthreads();
    for (int d = 1; d < RPB; d <<= 1) {
        u32 a = 0u;
        if (t < RPB && t >= d) a = o[t - d];
        __syncthreads();
        if (t < RPB) o[t] += a;
        __syncthreads();
    }
    if (t < RPB) { u32 e = o[t] - c[t]; o[t] = e; cur[t] = e; }
    __syncthreads();

    // scatter LDS->LDS into row-sorted eB (rk < cnt <= CAP by construction)
    for (u32 j = (u32)t; j < cnt; j += 1024u) {
        int2 e = eA[j];
        u32 rl = (u32)e.x >> 17;
        u32 rk = atomicAdd(&cur[rl], 1u);
        eB[rk] = make_int2(e.x & 0x1FFFF, e.y);
    }
    __syncthreads();

    // phase C: one row per 8-lane group, 8 dims/lane, no cross-lane reduce
    const int rows = min(RPB, N_NODES - b * RPB);
    const int g  = t >> 3;            // 0..127: local row
    const int dg = t & 7;             // dim group (8 dims = one uint4)

    float a0 = 0.f, a1 = 0.f, a2 = 0.f, a3 = 0.f;
    float a4 = 0.f, a5 = 0.f, a6 = 0.f, a7 = 0.f;

    u32 jb = 0u, jend = 0u;
    if (g < rows) {
        jb = o[g];
        jend = min(jb + c[g], (u32)CAP);
    }

    u32 j = jb;
    for (; j + 3u < jend; j += 4u) {
        int2 e0 = eB[j];                  // 8-lane broadcast (conflict-free)
        int2 e1 = eB[j + 1u];
        int2 e2 = eB[j + 2u];
        int2 e3 = eB[j + 3u];
        float v0 = __int_as_float(e0.y);
        float v1 = __int_as_float(e1.y);
        float v2 = __int_as_float(e2.y);
        float v3 = __int_as_float(e3.y);
        uint4 h0 = ((const uint4*)(hbf + (size_t)e0.x * D))[dg];
        uint4 h1 = ((const uint4*)(hbf + (size_t)e1.x * D))[dg];
        uint4 h2 = ((const uint4*)(hbf + (size_t)e2.x * D))[dg];
        uint4 h3 = ((const uint4*)(hbf + (size_t)e3.x * D))[dg];
        a0 += v0 * bflo(h0.x); a1 += v0 * bfhi(h0.x);
        a2 += v0 * bflo(h0.y); a3 += v0 * bfhi(h0.y);
        a4 += v0 * bflo(h0.z); a5 += v0 * bfhi(h0.z);
        a6 += v0 * bflo(h0.w); a7 += v0 * bfhi(h0.w);
        a0 += v1 * bflo(h1.x); a1 += v1 * bfhi(h1.x);
        a2 += v1 * bflo(h1.y); a3 += v1 * bfhi(h1.y);
        a4 += v1 * bflo(h1.z); a5 += v1 * bfhi(h1.z);
        a6 += v1 * bflo(h1.w); a7 += v1 * bfhi(h1.w);
        a0 += v2 * bflo(h2.x); a1 += v2 * bfhi(h2.x);
        a2 += v2 * bflo(h2.y); a3 += v2 * bfhi(h2.y);
        a4 += v2 * bflo(h2.z); a5 += v2 * bfhi(h2.z);
        a6 += v2 * bflo(h2.w); a7 += v2 * bfhi(h2.w);
        a0 += v3 * bflo(h3.x); a1 += v3 * bfhi(h3.x);
        a2 += v3 * bflo(h3.y); a3 += v3 * bfhi(h3.y);
        a4 += v3 * bflo(h3.z); a5 += v3 * bfhi(h3.z);
        a6 += v3 * bflo(h3.w); a7 += v3 * bfhi(h3.w);
    }
    for (; j < jend; j++) {
        int2 e0 = eB[j];
        float v0 = __int_as_float(e0.y);
        uint4 h0 = ((const uint4*)(hbf + (size_t)e0.x * D))[dg];
        a0 += v0 * bflo(h0.x); a1 += v0 * bfhi(h0.x);
        a2 += v0 * bflo(h0.y); a3 += v0 * bfhi(h0.y);
        a4 += v0 * bflo(h0.z); a5 += v0 * bfhi(h0.z);
        a6 += v0 * bflo(h0.w); a7 += v0 * bfhi(h0.w);
    }

    // epilogue: all lanes active (8 lanes x 8 dims per row)
    if (g < rows) {
        const int grow = b * RPB + g;
        uint4 hr = ((const uint4*)(hbf + (size_t)grow * D))[dg];
        float4 s0 = ((const float4*)skip)[2 * dg];
        float4 s1 = ((const float4*)skip)[2 * dg + 1];
        float4 b0 = ((const float4*)bias)[2 * dg];
        float4 b1 = ((const float4*)bias)[2 * dg + 1];
        float4 x0, x1;
        x0.x = selu(bflo(hr.x) * s0.x + b0.x + a0);
        x0.y = selu(bfhi(hr.x) * s0.y + b0.y + a1);
        x0.z = selu(bflo(hr.y) * s0.z + b0.z + a2);
        x0.w = selu(bfhi(hr.y) * s0.w + b0.w + a3);
        x1.x = selu(bflo(hr.z) * s1.x + b1.x + a4);
        x1.y = selu(bfhi(hr.z) * s1.y + b1.y + a5);
        x1.z = selu(bflo(hr.w) * s1.z + b1.z + a6);
        x1.w = selu(bfhi(hr.w) * s1.w + b1.w + a7);
        ((float4*)(out + (size_t)grow * D))[2 * dg]     = x0;
        ((float4*)(out + (size_t)grow * D))[2 * dg + 1] = x1;
    }
}

extern "C" void kernel_launch(void* const* d_in, const int* in_sizes, int n_in,
                              void* d_out, int out_size, void* d_ws, size_t ws_size,
                              hipStream_t stream)
{
    const float* feat = (const float*)d_in[0];
    const float* kern = (const float*)d_in[1];
    const float* bias = (const float*)d_in[2];
    const float* skip = (const float*)d_in[3];
    const int*   erow = (const int*)d_in[4];
    const int*   ecol = (const int*)d_in[5];
    const float* eval = (const float*)d_in[6];
    float* out = (float*)d_out;

    // workspace layout (all segments 16B-aligned)
    u16*  hbf   = (u16*)d_ws;                            // 6,400,000 u16 (12.8 MB)
    u32*  poff  = (u32*)(hbf + (size_t)N_NODES * D);     // 784*784 u32 (2.46 MB)
    int2* sedge = (int2*)(poff + (size_t)NHB * POFF_ROW); // 784*2048 int2 (12.85 MB)
    // total ~28.1 MB

    hipLaunchKernelGGL(fused_gemm_sort, dim3(NGB + NHB), dim3(256), 0, stream,
                       feat, kern, erow, ecol, eval, hbf, sedge, poff);
    hipLaunchKernelGGL(agg_kernel, dim3(NBUK), dim3(1024), 0, stream,
                       poff, sedge, hbf, skip, bias, out);
}

// Round 7
// 166.155 us; speedup vs baseline: 1.1738x; 1.0130x over previous
//
#include <hip/hip_runtime.h>
#include <math.h>

#define N_NODES 100000
#define N_EDGES 1600000
#define D 64
#define RPB 128                  // rows per bucket
#define NBUK 782                 // ceil(N_NODES/128)
#define CAP 3072                 // LDS edge buffer (bucket mean 2048, +22 sigma)
#define NGB 782                  // gemm blocks (128 rows each)
#define NHB 784                  // sort blocks (FIRST in grid: poles start at t=0)
#define EPB 2048                 // edges per sort block (784*2048 >= 1.6M)
#define POFF_ROW 784             // u32 stride of poff[hb][*] (hb-major)

typedef unsigned int u32;
typedef unsigned short u16;

static __device__ __forceinline__ u32 f2bf(float x) {   // RNE fp32->bf16 (low 16)
    u32 u = __float_as_uint(x);
    u32 r = u + 0x7FFFu + ((u >> 16) & 1u);
    return r >> 16;
}
static __device__ __forceinline__ u32 pack2(float a, float b) {
    return f2bf(a) | (f2bf(b) << 16);
}
static __device__ __forceinline__ float bflo(u32 u) { return __uint_as_float(u << 16); }
static __device__ __forceinline__ float bfhi(u32 u) { return __uint_as_float(u & 0xFFFF0000u); }
static __device__ __forceinline__ float selu(float x) {
    const float scale = 1.0507009873554805f;
    const float alpha = 1.6732632423543772f;
    return x > 0.f ? scale * x : scale * alpha * (expf(x) - 1.f);
}
// 64-lane inclusive scan in-register (no barriers)
static __device__ __forceinline__ u32 wave_iscan(u32 x, int lane) {
    #pragma unroll
    for (int d = 1; d < 64; d <<= 1) {
        u32 y = __shfl_up(x, d, 64);
        if (lane >= d) x += y;
    }
    return x;
}

// ---------------------------------------------------------------------------
// K1 fused. Blocks [0,784): in-LDS counting sort of 2048 edges by 128-row
// bucket. erow staged in LDS; scan of 782 counts is shfl-based (wave scans +
// 4 wave partials): 2 barriers instead of 16 -- sort blocks are all
// co-resident from t=0, so kernel time ~= per-block critical path.
// Blocks [784,1566): bf16 h = feat @ kern (register-tiled 4r x 8c).
// ---------------------------------------------------------------------------
__global__ __launch_bounds__(256) void fused_gemm_sort(
    const float* __restrict__ feat, const float* __restrict__ kern,
    const int* __restrict__ erow, const int* __restrict__ ecol,
    const float* __restrict__ eval, u16* __restrict__ hbf,
    int2* __restrict__ sedge, u32* __restrict__ poff)
{
    __shared__ u32 smem[4400];   // 17.6 KB: gemm uses 16 KB; sort uses all
    const int t = threadIdx.x;

    if (blockIdx.x >= NHB) {
        float* ks = (float*)smem;   // 64x64 kernel, row-major [k][c]
        {
            const float4* k4 = (const float4*)kern;
            float4* ks4 = (float4*)ks;
            #pragma unroll
            for (int i = 0; i < 4; i++) ks4[t + 256 * i] = k4[t + 256 * i];
        }
        __syncthreads();

        const int cgi  = t & 7;                      // 8 col-groups (8 cols)
        const int rg   = t >> 3;                     // 32 row-groups (4 rows)
        const int row0 = (blockIdx.x - NHB) * RPB + rg * 4;

        float4 acc[4][2];
        #pragma unroll
        for (int r = 0; r < 4; r++)
            #pragma unroll
            for (int i = 0; i < 2; i++)
                acc[r][i] = make_float4(0.f, 0.f, 0.f, 0.f);

        #pragma unroll 4
        for (int s = 0; s < 16; s++) {               // k4-step: 4 k-values
            float4 f[4];
            #pragma unroll
            for (int r = 0; r < 4; r++) {
                int row = min(row0 + r, N_NODES - 1);
                f[r] = ((const float4*)(feat + (size_t)row * D))[s];
            }
            float4 kk[4][2];
            #pragma unroll
            for (int kv = 0; kv < 4; kv++)
                #pragma unroll
                for (int i = 0; i < 2; i++)
                    kk[kv][i] = ((const float4*)(ks + (s * 4 + kv) * D))[cgi * 2 + i];
            #pragma unroll
            for (int r = 0; r < 4; r++) {
                #pragma unroll
                for (int kv = 0; kv < 4; kv++) {
                    float fv = (&f[r].x)[kv];
                    #pragma unroll
                    for (int i = 0; i < 2; i++) {
                        acc[r][i].x += fv * kk[kv][i].x;
                        acc[r][i].y += fv * kk[kv][i].y;
                        acc[r][i].z += fv * kk[kv][i].z;
                        acc[r][i].w += fv * kk[kv][i].w;
                    }
                }
            }
        }

        #pragma unroll
        for (int r = 0; r < 4; r++) {
            int row = row0 + r;
            if (row < N_NODES) {
                uint4 o;
                o.x = pack2(acc[r][0].x, acc[r][0].y);
                o.y = pack2(acc[r][0].z, acc[r][0].w);
                o.z = pack2(acc[r][1].x, acc[r][1].y);
                o.w = pack2(acc[r][1].z, acc[r][1].w);
                ((uint4*)(hbf + (size_t)row * D))[cgi] = o;
            }
        }
    } else {
        u32* er   = smem;                 // 2048 staged erow (0xFFFFFFFF = OOB)
        u32* c    = er + EPB;             // 782 counts
        u32* o    = c + NBUK;             // 783 offsets
        u32* cu   = o + NBUK + 1;         // 782 cursors
        u32* part = cu + NBUK;            // 4 wave partials  (total 4399 u32)

        for (int i = t; i < NBUK; i += 256) c[i] = 0u;
        __syncthreads();

        const int hb   = blockIdx.x;
        const int base = hb * EPB;
        const int lane = t & 63;
        const int w    = t >> 6;

        // pass 1: stage erow in LDS + bucket count (native u32 LDS atomics)
        #pragma unroll
        for (int k = 0; k < 8; k++) {
            int i = base + k * 256 + t;
            u32 r = 0xFFFFFFFFu;
            if (i < N_EDGES) { r = (u32)erow[i]; atomicAdd(&c[r >> 7], 1u); }
            er[k * 256 + t] = r;
        }
        __syncthreads();

        // shfl-based exclusive scan over 782 counts (4/thread, 2 barriers)
        const int i0 = t * 4;
        u32 p = 0u;
        #pragma unroll
        for (int jj = 0; jj < 4; jj++) { int i = i0 + jj; if (i < NBUK) p += c[i]; }
        u32 incl = wave_iscan(p, lane);
        if (lane == 63) part[w] = incl;
        __syncthreads();
        {
            u32 wp = 0u;
            #pragma unroll
            for (int ww = 0; ww < 4; ww++) if (ww < w) wp += part[ww];
            u32 run = incl - p + wp;
            #pragma unroll
            for (int jj = 0; jj < 4; jj++) {
                int i = i0 + jj;
                if (i < NBUK) { o[i] = run; cu[i] = run; run += c[i]; }
            }
            if (t == 0) o[NBUK] = part[0] + part[1] + part[2] + part[3];
        }
        __syncthreads();

        // pass 2: erow from LDS, scatter into private contiguous region
        #pragma unroll
        for (int k = 0; k < 8; k++) {
            int i = base + k * 256 + t;
            u32 r = er[k * 256 + t];
            if (r != 0xFFFFFFFFu) {
                u32 rk = atomicAdd(&cu[r >> 7], 1u);
                sedge[(size_t)hb * EPB + rk] =
                    make_int2(ecol[i] | (int)((r & 127u) << 17),
                              __float_as_int(eval[i]));
            }
        }

        // publish 783 offsets, hb-major: fully coalesced contiguous writes
        for (int i = t; i <= NBUK; i += 256)
            poff[(size_t)hb * POFF_ROW + i] = o[i];
    }
}

// ---------------------------------------------------------------------------
// K2: aggregation, edge-parallel staging with O(1) run lookup.
//  1) descriptor gather from hb-major poff; shfl-scan of 784 run lengths
//     (2 barriers, was 20); build runid[j] map (each run writes its ~2.6
//     entries) + combo[rid] = rs0-excl, so staging resolves its source with
//     2 independent LDS reads instead of a 10-deep binary-search chain.
//  2) Stage: edge-parallel; runid/combo lookup, single global load, write
//     eA, count row (LDS atomic).
//  3) shfl-based 128-row scan (2 barriers); LDS->LDS scatter into eB.
//  4) Phase C: one row per 8-lane group, 8 dims/lane, x4 unroll, no
//     cross-lane reduce; epilogue uses all 1024 lanes.
// ---------------------------------------------------------------------------
__global__ __launch_bounds__(1024) void agg_kernel(
    const u32* __restrict__ poff, const int2* __restrict__ sedge,
    const u16* __restrict__ hbf, const float* __restrict__ skip,
    const float* __restrict__ bias, float* __restrict__ out)
{
    __shared__ int2 eA[CAP];          // 24 KB staged (bucket-contiguous)
    __shared__ int2 eB[CAP];          // 24 KB row-sorted
    __shared__ u32 c[RPB];
    __shared__ u32 o[RPB];
    __shared__ u32 cur[RPB];
    __shared__ u32 combo[NHB];        // rs0[rid] - excl[rid]  (mod 2^32)
    __shared__ u16 runid[CAP];        // edge index -> run id
    __shared__ u32 wsum[16];
    __shared__ u32 wpre[16];
    __shared__ u32 cnt_sh;

    const int t = threadIdx.x;
    const int lane = t & 63;
    const int w = t >> 6;
    const int b = blockIdx.x;

    if (t < RPB) c[t] = 0u;

    // run descriptors: hb-major poff -> scattered 4B loads, L2-hot (97x reuse)
    u32 mylen = 0u, s0 = 0u;
    if (t < NHB) {
        const u32* pr = poff + (size_t)t * POFF_ROW + b;
        s0    = pr[0];
        mylen = pr[1] - s0;
    }
    // shfl scan of 784 run lengths: wave scans + 16 wave partials
    u32 incl = wave_iscan(mylen, lane);
    if (lane == 63) wsum[w] = incl;
    __syncthreads();
    if (w == 0) {
        u32 v = (lane < 16) ? wsum[lane] : 0u;
        u32 pp = wave_iscan(v, lane);
        if (lane < 16) wpre[lane] = pp - v;       // exclusive wave prefix
        if (lane == 15) cnt_sh = min(pp, (u32)CAP);
    }
    __syncthreads();
    incl += wpre[w];
    const u32 excl = incl - mylen;
    if (t < NHB) {
        combo[t] = s0 - excl;                      // wrapping arithmetic
        for (u32 j = excl; j < incl; j++)
            if (j < (u32)CAP) runid[j] = (u16)t;
    }
    __syncthreads();

    const u32 cnt = cnt_sh;

    // stage: edge-parallel, O(1) run lookup, single global read, row count
    for (u32 j = (u32)t; j < cnt; j += 1024u) {
        u32 rid = (u32)runid[j];
        u32 src = rid * (u32)EPB + combo[rid] + j; // == rid*EPB + rs0 + (j-excl)
        int2 e = sedge[(size_t)src];
        eA[j] = e;
        atomicAdd(&c[(u32)e.x >> 17], 1u);
    }
    __syncthreads();

    // shfl-based exclusive scan over 128 row counts (2 barriers)
    {
        u32 x = (t < RPB) ? c[t] : 0u;
        u32 ri = wave_iscan(x, lane);
        if (lane == 63) wsum[w] = ri;
        __syncthreads();
        if (t < RPB) {
            u32 add = (w == 1) ? wsum[0] : 0u;
            u32 e = ri + add - x;
            o[t] = e; cur[t] = e;
        }
        __syncthreads();
    }

    // scatter LDS->LDS into row-sorted eB (rk < cnt <= CAP by construction)
    for (u32 j = (u32)t; j < cnt; j += 1024u) {
        int2 e = eA[j];
        u32 rl = (u32)e.x >> 17;
        u32 rk = atomicAdd(&cur[rl], 1u);
        eB[rk] = make_int2(e.x & 0x1FFFF, e.y);
    }
    __syncthreads();

    // phase C: one row per 8-lane group, 8 dims/lane, no cross-lane reduce
    const int rows = min(RPB, N_NODES - b * RPB);
    const int g  = t >> 3;            // 0..127: local row
    const int dg = t & 7;             // dim group (8 dims = one uint4)

    float a0 = 0.f, a1 = 0.f, a2 = 0.f, a3 = 0.f;
    float a4 = 0.f, a5 = 0.f, a6 = 0.f, a7 = 0.f;

    u32 jb = 0u, jend = 0u;
    if (g < rows) {
        jb = o[g];
        jend = min(jb + c[g], (u32)CAP);
    }

    u32 j = jb;
    for (; j + 3u < jend; j += 4u) {
        int2 e0 = eB[j];                  // 8-lane broadcast (conflict-free)
        int2 e1 = eB[j + 1u];
        int2 e2 = eB[j + 2u];
        int2 e3 = eB[j + 3u];
        float v0 = __int_as_float(e0.y);
        float v1 = __int_as_float(e1.y);
        float v2 = __int_as_float(e2.y);
        float v3 = __int_as_float(e3.y);
        uint4 h0 = ((const uint4*)(hbf + (size_t)e0.x * D))[dg];
        uint4 h1 = ((const uint4*)(hbf + (size_t)e1.x * D))[dg];
        uint4 h2 = ((const uint4*)(hbf + (size_t)e2.x * D))[dg];
        uint4 h3 = ((const uint4*)(hbf + (size_t)e3.x * D))[dg];
        a0 += v0 * bflo(h0.x); a1 += v0 * bfhi(h0.x);
        a2 += v0 * bflo(h0.y); a3 += v0 * bfhi(h0.y);
        a4 += v0 * bflo(h0.z); a5 += v0 * bfhi(h0.z);
        a6 += v0 * bflo(h0.w); a7 += v0 * bfhi(h0.w);
        a0 += v1 * bflo(h1.x); a1 += v1 * bfhi(h1.x);
        a2 += v1 * bflo(h1.y); a3 += v1 * bfhi(h1.y);
        a4 += v1 * bflo(h1.z); a5 += v1 * bfhi(h1.z);
        a6 += v1 * bflo(h1.w); a7 += v1 * bfhi(h1.w);
        a0 += v2 * bflo(h2.x); a1 += v2 * bfhi(h2.x);
        a2 += v2 * bflo(h2.y); a3 += v2 * bfhi(h2.y);
        a4 += v2 * bflo(h2.z); a5 += v2 * bfhi(h2.z);
        a6 += v2 * bflo(h2.w); a7 += v2 * bfhi(h2.w);
        a0 += v3 * bflo(h3.x); a1 += v3 * bfhi(h3.x);
        a2 += v3 * bflo(h3.y); a3 += v3 * bfhi(h3.y);
        a4 += v3 * bflo(h3.z); a5 += v3 * bfhi(h3.z);
        a6 += v3 * bflo(h3.w); a7 += v3 * bfhi(h3.w);
    }
    for (; j < jend; j++) {
        int2 e0 = eB[j];
        float v0 = __int_as_float(e0.y);
        uint4 h0 = ((const uint4*)(hbf + (size_t)e0.x * D))[dg];
        a0 += v0 * bflo(h0.x); a1 += v0 * bfhi(h0.x);
        a2 += v0 * bflo(h0.y); a3 += v0 * bfhi(h0.y);
        a4 += v0 * bflo(h0.z); a5 += v0 * bfhi(h0.z);
        a6 += v0 * bflo(h0.w); a7 += v0 * bfhi(h0.w);
    }

    // epilogue: all lanes active (8 lanes x 8 dims per row)
    if (g < rows) {
        const int grow = b * RPB + g;
        uint4 hr = ((const uint4*)(hbf + (size_t)grow * D))[dg];
        float4 s0v = ((const float4*)skip)[2 * dg];
        float4 s1v = ((const float4*)skip)[2 * dg + 1];
        float4 b0v = ((const float4*)bias)[2 * dg];
        float4 b1v = ((const float4*)bias)[2 * dg + 1];
        float4 x0, x1;
        x0.x = selu(bflo(hr.x) * s0v.x + b0v.x + a0);
        x0.y = selu(bfhi(hr.x) * s0v.y + b0v.y + a1);
        x0.z = selu(bflo(hr.y) * s0v.z + b0v.z + a2);
        x0.w = selu(bfhi(hr.y) * s0v.w + b0v.w + a3);
        x1.x = selu(bflo(hr.z) * s1v.x + b1v.x + a4);
        x1.y = selu(bfhi(hr.z) * s1v.y + b1v.y + a5);
        x1.z = selu(bflo(hr.w) * s1v.z + b1v.z + a6);
        x1.w = selu(bfhi(hr.w) * s1v.w + b1v.w + a7);
        ((float4*)(out + (size_t)grow * D))[2 * dg]     = x0;
        ((float4*)(out + (size_t)grow * D))[2 * dg + 1] = x1;
    }
}

extern "C" void kernel_launch(void* const* d_in, const int* in_sizes, int n_in,
                              void* d_out, int out_size, void* d_ws, size_t ws_size,
                              hipStream_t stream)
{
    const float* feat = (const float*)d_in[0];
    const float* kern = (const float*)d_in[1];
    const float* bias = (const float*)d_in[2];
    const float* skip = (const float*)d_in[3];
    const int*   erow = (const int*)d_in[4];
    const int*   ecol = (const int*)d_in[5];
    const float* eval = (const float*)d_in[6];
    float* out = (float*)d_out;

    // workspace layout (all segments 16B-aligned)
    u16*  hbf   = (u16*)d_ws;                             // 6,400,000 u16 (12.8 MB)
    u32*  poff  = (u32*)(hbf + (size_t)N_NODES * D);      // 784*784 u32 (2.46 MB)
    int2* sedge = (int2*)(poff + (size_t)NHB * POFF_ROW); // 784*2048 int2 (12.85 MB)
    // total ~28.1 MB

    hipLaunchKernelGGL(fused_gemm_sort, dim3(NGB + NHB), dim3(256), 0, stream,
                       feat, kern, erow, ecol, eval, hbf, sedge, poff);
    hipLaunchKernelGGL(agg_kernel, dim3(NBUK), dim3(1024), 0, stream,
                       poff, sedge, hbf, skip, bias, out);
}

// Round 8
// 161.880 us; speedup vs baseline: 1.2048x; 1.0264x over previous
//
#include <hip/hip_runtime.h>
#include <math.h>

#define N_NODES 100000
#define N_EDGES 1600000
#define D 64
#define RPB 128                  // rows per bucket
#define NBUK 782                 // ceil(N_NODES/128)
#define CAP 3072                 // LDS edge buffer (bucket mean 2048, +22 sigma)
#define NGB 782                  // gemm blocks (128 rows each)
#define NHB 784                  // sort blocks (FIRST in grid: poles start at t=0)
#define EPB 2048                 // edges per sort block (784*2048 >= 1.6M)
#define POFF_ROW 784             // u32 stride of poff[hb][*] (hb-major)

typedef unsigned int u32;
typedef unsigned short u16;

static __device__ __forceinline__ u32 f2bf(float x) {   // RNE fp32->bf16 (low 16)
    u32 u = __float_as_uint(x);
    u32 r = u + 0x7FFFu + ((u >> 16) & 1u);
    return r >> 16;
}
static __device__ __forceinline__ u32 pack2(float a, float b) {
    return f2bf(a) | (f2bf(b) << 16);
}
static __device__ __forceinline__ float bflo(u32 u) { return __uint_as_float(u << 16); }
static __device__ __forceinline__ float bfhi(u32 u) { return __uint_as_float(u & 0xFFFF0000u); }
static __device__ __forceinline__ float selu(float x) {
    const float scale = 1.0507009873554805f;
    const float alpha = 1.6732632423543772f;
    return x > 0.f ? scale * x : scale * alpha * (expf(x) - 1.f);
}
// 64-lane inclusive scan in-register (no barriers)
static __device__ __forceinline__ u32 wave_iscan(u32 x, int lane) {
    #pragma unroll
    for (int d = 1; d < 64; d <<= 1) {
        u32 y = __shfl_up(x, d, 64);
        if (lane >= d) x += y;
    }
    return x;
}

// ---------------------------------------------------------------------------
// K1 fused. Blocks [0,784): in-LDS counting sort of 2048 edges by 128-row
// bucket. NEW: the sorted edges are scattered into a 16 KB LDS tile and then
// FLUSHED with 8 coalesced 8-B streaks -- the previous random 8-B global
// stores partial-line-amplified WRITE_SIZE to ~68 MB (ideal ~27) because the
// concurrent gemm feat stream evicted partially-written L2 lines. Count and
// offset tables are overlaid in-place (counts -> offsets) so LDS stays at
// 22.7 KB and all 1566 blocks remain co-resident (7 blocks/CU).
// Blocks [784,1566): bf16 h = feat @ kern (register-tiled 4r x 8c).
// ---------------------------------------------------------------------------
__global__ __launch_bounds__(256) void fused_gemm_sort(
    const float* __restrict__ feat, const float* __restrict__ kern,
    const int* __restrict__ erow, const int* __restrict__ ecol,
    const float* __restrict__ eval, u16* __restrict__ hbf,
    int2* __restrict__ sedge, u32* __restrict__ poff)
{
    __shared__ u32 smem[5665];   // 22.7 KB: gemm uses 16 KB; sort uses all
    const int t = threadIdx.x;

    if (blockIdx.x >= NHB) {
        float* ks = (float*)smem;   // 64x64 kernel, row-major [k][c]
        {
            const float4* k4 = (const float4*)kern;
            float4* ks4 = (float4*)ks;
            #pragma unroll
            for (int i = 0; i < 4; i++) ks4[t + 256 * i] = k4[t + 256 * i];
        }
        __syncthreads();

        const int cgi  = t & 7;                      // 8 col-groups (8 cols)
        const int rg   = t >> 3;                     // 32 row-groups (4 rows)
        const int row0 = (blockIdx.x - NHB) * RPB + rg * 4;

        float4 acc[4][2];
        #pragma unroll
        for (int r = 0; r < 4; r++)
            #pragma unroll
            for (int i = 0; i < 2; i++)
                acc[r][i] = make_float4(0.f, 0.f, 0.f, 0.f);

        #pragma unroll 4
        for (int s = 0; s < 16; s++) {               // k4-step: 4 k-values
            float4 f[4];
            #pragma unroll
            for (int r = 0; r < 4; r++) {
                int row = min(row0 + r, N_NODES - 1);
                f[r] = ((const float4*)(feat + (size_t)row * D))[s];
            }
            float4 kk[4][2];
            #pragma unroll
            for (int kv = 0; kv < 4; kv++)
                #pragma unroll
                for (int i = 0; i < 2; i++)
                    kk[kv][i] = ((const float4*)(ks + (s * 4 + kv) * D))[cgi * 2 + i];
            #pragma unroll
            for (int r = 0; r < 4; r++) {
                #pragma unroll
                for (int kv = 0; kv < 4; kv++) {
                    float fv = (&f[r].x)[kv];
                    #pragma unroll
                    for (int i = 0; i < 2; i++) {
                        acc[r][i].x += fv * kk[kv][i].x;
                        acc[r][i].y += fv * kk[kv][i].y;
                        acc[r][i].z += fv * kk[kv][i].z;
                        acc[r][i].w += fv * kk[kv][i].w;
                    }
                }
            }
        }

        #pragma unroll
        for (int r = 0; r < 4; r++) {
            int row = row0 + r;
            if (row < N_NODES) {
                uint4 o;
                o.x = pack2(acc[r][0].x, acc[r][0].y);
                o.y = pack2(acc[r][0].z, acc[r][0].w);
                o.z = pack2(acc[r][1].x, acc[r][1].y);
                o.w = pack2(acc[r][1].z, acc[r][1].w);
                ((uint4*)(hbf + (size_t)row * D))[cgi] = o;
            }
        }
    } else {
        int2* tile = (int2*)smem;          // 2048 int2 = 16 KB sorted tile
        u32* co    = smem + 4096;          // 783: counts, then offsets in-place
        u32* cu    = co + 783;             // 782 cursors
        u32* part  = cu + 782;             // 4 wave partials   (total 5665 u32)

        for (int i = t; i < 783; i += 256) co[i] = 0u;
        __syncthreads();

        const int hb   = blockIdx.x;
        const int base = hb * EPB;
        const int lane = t & 63;
        const int w    = t >> 6;

        // pass 1: bucket count (native u32 LDS atomics), coalesced erow reads
        #pragma unroll
        for (int k = 0; k < 8; k++) {
            int i = base + k * 256 + t;
            if (i < N_EDGES) atomicAdd(&co[(u32)erow[i] >> 7], 1u);
        }
        __syncthreads();

        // shfl-based exclusive scan over 782 counts, offsets written in-place
        const int i0 = t * 4;
        u32 p = 0u;
        #pragma unroll
        for (int jj = 0; jj < 4; jj++) { int i = i0 + jj; if (i < NBUK) p += co[i]; }
        u32 incl = wave_iscan(p, lane);
        if (lane == 63) part[w] = incl;
        __syncthreads();
        {
            u32 wp = 0u;
            #pragma unroll
            for (int ww = 0; ww < 4; ww++) if (ww < w) wp += part[ww];
            u32 run = incl - p + wp;
            #pragma unroll
            for (int jj = 0; jj < 4; jj++) {
                int i = i0 + jj;
                if (i < NBUK) { u32 cv = co[i]; co[i] = run; cu[i] = run; run += cv; }
            }
            if (t == 0) co[NBUK] = part[0] + part[1] + part[2] + part[3];
        }
        __syncthreads();

        // pass 2: re-read erow (L2-hot), scatter into LDS tile
        #pragma unroll
        for (int k = 0; k < 8; k++) {
            int i = base + k * 256 + t;
            if (i < N_EDGES) {
                u32 r = (u32)erow[i];
                u32 rk = atomicAdd(&cu[r >> 7], 1u);
                tile[rk] = make_int2(ecol[i] | (int)((r & 127u) << 17),
                                     __float_as_int(eval[i]));
            }
        }
        __syncthreads();

        // flush: fully coalesced contiguous int2 stores (slots >= cnt are
        // garbage but never read -- poff runs only cover [0, cnt))
        #pragma unroll
        for (int k = 0; k < 8; k++)
            sedge[(size_t)hb * EPB + k * 256 + t] = tile[k * 256 + t];

        // publish 783 offsets, hb-major: fully coalesced contiguous writes
        for (int i = t; i <= NBUK; i += 256)
            poff[(size_t)hb * POFF_ROW + i] = co[i];
    }
}

// ---------------------------------------------------------------------------
// K2: aggregation. Staging (O(1) runid lookup) unchanged from round 7.
// NEW in phase C:
//  - degree-ranked row assignment: counting-sort the 128 rows by degree
//    (64 bins + shfl scan) so each wave's 8 rows have ~equal degree ->
//    lockstep max-degree waste drops from ~35% to ~5%.
//  - explicit double-buffered prefetch: load batch B's 4 uint4 gathers while
//    FMA-ing batch A (named registers, no runtime-indexed arrays).
//    __launch_bounds__(1024, 8) pins VGPR<=64 so both batches stay resident
//    (round 7's VGPR=32 couldn't pipeline -> gather-latency-bound).
// ---------------------------------------------------------------------------
__global__ __launch_bounds__(1024, 8) void agg_kernel(
    const u32* __restrict__ poff, const int2* __restrict__ sedge,
    const u16* __restrict__ hbf, const float* __restrict__ skip,
    const float* __restrict__ bias, float* __restrict__ out)
{
    __shared__ int2 eA[CAP];          // 24 KB staged (bucket-contiguous)
    __shared__ int2 eB[CAP];          // 24 KB row-sorted
    __shared__ u32 c[RPB];
    __shared__ u32 o[RPB];
    __shared__ u32 cur[RPB];
    __shared__ u32 combo[NHB];        // rs0[rid] - excl[rid]  (mod 2^32)
    __shared__ u16 runid[CAP];        // edge index -> run id
    __shared__ u32 wsum[16];
    __shared__ u32 wpre[16];
    __shared__ u32 dbin[64];          // degree histogram bins
    __shared__ u32 perm[RPB];         // degree-ranked row permutation
    __shared__ u32 cnt_sh;

    const int t = threadIdx.x;
    const int lane = t & 63;
    const int w = t >> 6;
    const int b = blockIdx.x;

    if (t < RPB) c[t] = 0u;
    if (t < 64) dbin[t] = 0u;

    // run descriptors: hb-major poff -> scattered 4B loads, L2-hot (97x reuse)
    u32 mylen = 0u, s0 = 0u;
    if (t < NHB) {
        const u32* pr = poff + (size_t)t * POFF_ROW + b;
        s0    = pr[0];
        mylen = pr[1] - s0;
    }
    // shfl scan of 784 run lengths: wave scans + 16 wave partials
    u32 incl = wave_iscan(mylen, lane);
    if (lane == 63) wsum[w] = incl;
    __syncthreads();
    if (w == 0) {
        u32 v = (lane < 16) ? wsum[lane] : 0u;
        u32 pp = wave_iscan(v, lane);
        if (lane < 16) wpre[lane] = pp - v;       // exclusive wave prefix
        if (lane == 15) cnt_sh = min(pp, (u32)CAP);
    }
    __syncthreads();
    incl += wpre[w];
    const u32 excl = incl - mylen;
    if (t < NHB) {
        combo[t] = s0 - excl;                      // wrapping arithmetic
        for (u32 j = excl; j < incl; j++)
            if (j < (u32)CAP) runid[j] = (u16)t;
    }
    __syncthreads();

    const u32 cnt = cnt_sh;

    // stage: edge-parallel, O(1) run lookup, single global read, row count
    for (u32 j = (u32)t; j < cnt; j += 1024u) {
        u32 rid = (u32)runid[j];
        u32 src = rid * (u32)EPB + combo[rid] + j; // == rid*EPB + rs0 + (j-excl)
        int2 e = sedge[(size_t)src];
        eA[j] = e;
        atomicAdd(&c[(u32)e.x >> 17], 1u);
    }
    __syncthreads();

    // shfl-based exclusive scan over 128 row counts (2 barriers)
    {
        u32 x = (t < RPB) ? c[t] : 0u;
        u32 ri = wave_iscan(x, lane);
        if (lane == 63) wsum[w] = ri;
        __syncthreads();
        if (t < RPB) {
            u32 add = (w == 1) ? wsum[0] : 0u;
            u32 e = ri + add - x;
            o[t] = e; cur[t] = e;
        }
        __syncthreads();
    }

    // degree histogram (dbin zeroed at top; c stable since stage barrier)
    if (t < RPB) atomicAdd(&dbin[min(c[t], 63u)], 1u);

    // scatter LDS->LDS into row-sorted eB (rk < cnt <= CAP by construction)
    for (u32 j = (u32)t; j < cnt; j += 1024u) {
        int2 e = eA[j];
        u32 rl = (u32)e.x >> 17;
        u32 rk = atomicAdd(&cur[rl], 1u);
        eB[rk] = make_int2(e.x & 0x1FFFF, e.y);
    }
    __syncthreads();

    // degree-bucket exclusive scan + place permutation
    if (w == 0) {
        u32 v = dbin[lane];
        u32 sc = wave_iscan(v, lane);
        dbin[lane] = sc - v;               // exclusive offsets (become cursors)
    }
    __syncthreads();
    if (t < RPB) {
        u32 r = atomicAdd(&dbin[min(c[t], 63u)], 1u);
        perm[r] = (u32)t;
    }
    __syncthreads();

    // phase C: one row per 8-lane group (degree-ranked), 8 dims/lane,
    // double-buffered 4-wide prefetch, no cross-lane reduce
    const int rows = min(RPB, N_NODES - b * RPB);
    const int g  = t >> 3;            // 0..127: group
    const int dg = t & 7;             // dim group (8 dims = one uint4)

    float a0 = 0.f, a1 = 0.f, a2 = 0.f, a3 = 0.f;
    float a4 = 0.f, a5 = 0.f, a6 = 0.f, a7 = 0.f;

    const u32 rl = perm[g];           // degree-ranked local row
    u32 jb   = o[rl];
    u32 jend = min(jb + c[rl], (u32)CAP);

#define LD4(J, H0,H1,H2,H3, V0,V1,V2,V3) do {                         \
        int2 _e0 = eB[(J)];   int2 _e1 = eB[(J)+1u];                  \
        int2 _e2 = eB[(J)+2u]; int2 _e3 = eB[(J)+3u];                 \
        V0 = __int_as_float(_e0.y); V1 = __int_as_float(_e1.y);       \
        V2 = __int_as_float(_e2.y); V3 = __int_as_float(_e3.y);       \
        H0 = ((const uint4*)(hbf + (size_t)_e0.x * D))[dg];           \
        H1 = ((const uint4*)(hbf + (size_t)_e1.x * D))[dg];           \
        H2 = ((const uint4*)(hbf + (size_t)_e2.x * D))[dg];           \
        H3 = ((const uint4*)(hbf + (size_t)_e3.x * D))[dg];           \
    } while (0)
#define FMA1(H, V) do {                                               \
        a0 += (V) * bflo((H).x); a1 += (V) * bfhi((H).x);             \
        a2 += (V) * bflo((H).y); a3 += (V) * bfhi((H).y);             \
        a4 += (V) * bflo((H).z); a5 += (V) * bfhi((H).z);             \
        a6 += (V) * bflo((H).w); a7 += (V) * bfhi((H).w);             \
    } while (0)

    u32 j = jb;
    {
        uint4 hA0, hA1, hA2, hA3, hB0, hB1, hB2, hB3;
        float vA0, vA1, vA2, vA3, vB0, vB1, vB2, vB3;
        if (j + 3u < jend) {
            LD4(j, hA0, hA1, hA2, hA3, vA0, vA1, vA2, vA3);
            j += 4u;
            while (j + 3u < jend) {
                LD4(j, hB0, hB1, hB2, hB3, vB0, vB1, vB2, vB3); // prefetch
                FMA1(hA0, vA0); FMA1(hA1, vA1);                 // consume A
                FMA1(hA2, vA2); FMA1(hA3, vA3);
                hA0 = hB0; hA1 = hB1; hA2 = hB2; hA3 = hB3;
                vA0 = vB0; vA1 = vB1; vA2 = vB2; vA3 = vB3;
                j += 4u;
            }
            FMA1(hA0, vA0); FMA1(hA1, vA1);
            FMA1(hA2, vA2); FMA1(hA3, vA3);
        }
    }
    for (; j < jend; j++) {
        int2 e0 = eB[j];
        float v0 = __int_as_float(e0.y);
        uint4 h0 = ((const uint4*)(hbf + (size_t)e0.x * D))[dg];
        FMA1(h0, v0);
    }
#undef LD4
#undef FMA1

    // epilogue: all lanes active (8 lanes x 8 dims per row)
    if (rl < (u32)rows) {
        const int grow = b * RPB + (int)rl;
        uint4 hr = ((const uint4*)(hbf + (size_t)grow * D))[dg];
        float4 s0v = ((const float4*)skip)[2 * dg];
        float4 s1v = ((const float4*)skip)[2 * dg + 1];
        float4 b0v = ((const float4*)bias)[2 * dg];
        float4 b1v = ((const float4*)bias)[2 * dg + 1];
        float4 x0, x1;
        x0.x = selu(bflo(hr.x) * s0v.x + b0v.x + a0);
        x0.y = selu(bfhi(hr.x) * s0v.y + b0v.y + a1);
        x0.z = selu(bflo(hr.y) * s0v.z + b0v.z + a2);
        x0.w = selu(bfhi(hr.y) * s0v.w + b0v.w + a3);
        x1.x = selu(bflo(hr.z) * s1v.x + b1v.x + a4);
        x1.y = selu(bfhi(hr.z) * s1v.y + b1v.y + a5);
        x1.z = selu(bflo(hr.w) * s1v.z + b1v.z + a6);
        x1.w = selu(bfhi(hr.w) * s1v.w + b1v.w + a7);
        ((float4*)(out + (size_t)grow * D))[2 * dg]     = x0;
        ((float4*)(out + (size_t)grow * D))[2 * dg + 1] = x1;
    }
}

extern "C" void kernel_launch(void* const* d_in, const int* in_sizes, int n_in,
                              void* d_out, int out_size, void* d_ws, size_t ws_size,
                              hipStream_t stream)
{
    const float* feat = (const float*)d_in[0];
    const float* kern = (const float*)d_in[1];
    const float* bias = (const float*)d_in[2];
    const float* skip = (const float*)d_in[3];
    const int*   erow = (const int*)d_in[4];
    const int*   ecol = (const int*)d_in[5];
    const float* eval = (const float*)d_in[6];
    float* out = (float*)d_out;

    // workspace layout (all segments 16B-aligned)
    u16*  hbf   = (u16*)d_ws;                             // 6,400,000 u16 (12.8 MB)
    u32*  poff  = (u32*)(hbf + (size_t)N_NODES * D);      // 784*784 u32 (2.46 MB)
    int2* sedge = (int2*)(poff + (size_t)NHB * POFF_ROW); // 784*2048 int2 (12.85 MB)
    // total ~28.1 MB

    hipLaunchKernelGGL(fused_gemm_sort, dim3(NGB + NHB), dim3(256), 0, stream,
                       feat, kern, erow, ecol, eval, hbf, sedge, poff);
    hipLaunchKernelGGL(agg_kernel, dim3(NBUK), dim3(1024), 0, stream,
                       poff, sedge, hbf, skip, bias, out);
}